// Round 4
// baseline (139.051 us; speedup 1.0000x reference)
//
#include <hip/hip_runtime.h>
#include <hip/hip_bf16.h>

#define DIM 8192
#define KSPLIT 16
#define PARTIAL_ELEMS (32 * DIM)   // one fp32 copy of the output per k-chunk
#define POISON 0xAAAAAAAAu         // harness re-poisons d_ws to 0xAA bytes before every timed launch

typedef __bf16 bf16x8 __attribute__((ext_vector_type(8)));
typedef float f32x4 __attribute__((ext_vector_type(4)));

__device__ __forceinline__ unsigned short f2bf(float f) {
  union { float f; unsigned u; } v; v.f = f;
  unsigned r = v.u + 0x7FFFu + ((v.u >> 16) & 1u);   // RNE
  return (unsigned short)(r >> 16);
}

// Single dispatch. grid: 512 = 32 mc (low 5 bits) x 16 kc; block 256 (4 waves).
// Each wg: partial out cols [mc*256,+256) over k [kc*512,+512) -> Ws[kc][32][8192],
// then split-K fan-in: last-arriving wg per mc (atomic counter starting at the
// known 0xAAAAAAAA poison) reduces the 16 partials for its columns into Out.
__global__ __launch_bounds__(256, 2)
void bcl_mfma_kernel(const float* __restrict__ X,
                     const float* __restrict__ Blk,
                     float* __restrict__ Ws,
                     unsigned* __restrict__ Cnt,
                     float* __restrict__ Out) {
  // x: [s:16][b0:2][kh:4][p:16][j:8] bf16 (32 KB): frag = contiguous 1KB
  __shared__ __align__(16) unsigned short Xl[16384];
  // blocks window: 47 slots x 512B, each repacked [qh:2][p:16][j:8]
  __shared__ __align__(16) unsigned short Wl[47 * 256];
  __shared__ unsigned last_flag;

  const int tid = threadIdx.x;
  const int mc  = blockIdx.x & 31;
  const int kc  = blockIdx.x >> 5;
  const int kbase = kc * 512;

  // ---- stage x (fp32->bf16). LDS stores linear (conflict-free).
  #pragma unroll
  for (int it = 0; it < 16; ++it) {
    const int L  = (tid + it * 256) << 2;     // elem index in Xl
    const int j4 = L & 7;
    const int p  = (L >> 3) & 15;
    const int kh = (L >> 7) & 3;
    const int b0 = (L >> 9) & 1;
    const int s  = (L >> 10) & 15;
    const int batch = b0 * 16 + p;
    const int kg = kbase + s * 32 + (kh >> 1) * 16 + (kh & 1) * 8 + j4;
    const float4 v = *reinterpret_cast<const float4*>(X + batch * DIM + kg);
    ushort4 u;
    u.x = f2bf(v.x); u.y = f2bf(v.y); u.z = f2bf(v.z); u.w = f2bf(v.w);
    *reinterpret_cast<ushort4*>(&Xl[L]) = u;
  }

  // ---- stage blocks window: slot w holds blocks[(dbase+w)&511] as [qh][p][j]
  const int dbase = (mc * 16 - kc * 32 - 31) & 511;
  for (int i = tid; i < 47 * 64; i += 256) {
    const int w  = i >> 6;
    const int r  = (i & 63) << 2;             // elem in repacked block
    const int qh = r >> 7;
    const int p  = (r >> 3) & 15;
    const int j4 = r & 7;
    const int d  = (dbase + w) & 511;
    const float4 v = *reinterpret_cast<const float4*>(Blk + d * 256 + p * 16 + qh * 8 + j4);
    ushort4 u;
    u.x = f2bf(v.x); u.y = f2bf(v.y); u.z = f2bf(v.z); u.w = f2bf(v.w);
    *reinterpret_cast<ushort4*>(&Wl[w * 256 + r]) = u;
  }

  __syncthreads();

  const int lane = tid & 63;
  const int wid  = tid >> 6;

  // x-frag (a-operand): lane l -> Xl[s*1024 + b0*512 + l*8]
  const unsigned short* Xb = &Xl[lane << 3];
  // blocks-frag (b-operand): lanes 0-31 slot w0, lanes 32-63 slot w0-1, each half
  // a contiguous 512B run -> conflict-free wave-contiguous 1KB ds_read_b128
  const unsigned short* Wb = &Wl[(((lane >> 5) ^ 1) << 8) + (((lane >> 4) & 1) << 7) + ((lane & 15) << 3)];

  f32x4 acc[4][2];
  #pragma unroll
  for (int t = 0; t < 4; ++t)
    #pragma unroll
    for (int b = 0; b < 2; ++b)
      acc[t][b] = (f32x4){0.f, 0.f, 0.f, 0.f};

  #pragma unroll 4
  for (int s = 0; s < 16; ++s) {
    const bf16x8 x0 = *reinterpret_cast<const bf16x8*>(Xb + (s << 10));
    const bf16x8 x1 = *reinterpret_cast<const bf16x8*>(Xb + (s << 10) + 512);
    #pragma unroll
    for (int t = 0; t < 4; ++t) {
      const int mt = (wid << 2) + t;
      const bf16x8 wf = *reinterpret_cast<const bf16x8*>(Wb + ((mt + 30 - 2 * s) << 8));
      acc[t][0] = __builtin_amdgcn_mfma_f32_16x16x32_bf16(x0, wf, acc[t][0], 0, 0, 0);
      acc[t][1] = __builtin_amdgcn_mfma_f32_16x16x32_bf16(x1, wf, acc[t][1], 0, 0, 0);
    }
  }

  // ---- epilogue: store partial. C/D 16x16 layout: col=lane&15, row=(lane>>4)*4+reg
  float* base = Ws + (size_t)kc * PARTIAL_ELEMS + mc * 256;
  #pragma unroll
  for (int t = 0; t < 4; ++t) {
    const int col = ((wid << 2) + t) * 16 + (lane & 15);
    #pragma unroll
    for (int b0 = 0; b0 < 2; ++b0) {
      const int brow = b0 * 16 + ((lane >> 4) << 2);
      #pragma unroll
      for (int r = 0; r < 4; ++r)
        base[(brow + r) * DIM + col] = acc[t][b0][r];
    }
  }

  // ---- split-K fan-in: last wg per mc reduces its columns into Out.
  __threadfence();                       // release: partials visible device-wide
  if (tid == 0) {
    const unsigned old = atomicAdd(&Cnt[mc], 1u);   // device scope
    last_flag = (old == POISON + (KSPLIT - 1)) ? 1u : 0u;
  }
  __syncthreads();
  if (last_flag) {
    __threadfence();                     // acquire: see all 16 partials
    const float4* Wf = (const float4*)Ws;
    float4* Of = (float4*)Out;
    #pragma unroll
    for (int it = 0; it < 8; ++it) {
      const int f   = tid + it * 256;    // 0..2047 over this mc's 32x256 tile
      const int row = f >> 6;
      const int c4  = f & 63;
      const int o   = row * (DIM / 4) + mc * 64 + c4;   // same layout in Ws & Out
      float4 a = Wf[o];
      #pragma unroll
      for (int k = 1; k < KSPLIT; ++k) {
        const float4 v = Wf[k * (PARTIAL_ELEMS / 4) + o];
        a.x += v.x; a.y += v.y; a.z += v.z; a.w += v.w;
      }
      Of[o] = a;
    }
  }
}

extern "C" void kernel_launch(void* const* d_in, const int* in_sizes, int n_in,
                              void* d_out, int out_size, void* d_ws, size_t ws_size,
                              hipStream_t stream) {
  const float* X   = (const float*)d_in[0];   // [32, 8192] fp32
  const float* Blk = (const float*)d_in[1];   // [512, 16, 16] fp32
  float* Ws  = (float*)d_ws;                  // 16 MB partials ...
  unsigned* Cnt = (unsigned*)((float*)d_ws + (size_t)KSPLIT * PARTIAL_ELEMS);  // ... + 32 counters
  float* Out = (float*)d_out;                 // [32, 8192] fp32
  bcl_mfma_kernel<<<dim3(512), dim3(256), 0, stream>>>(X, Blk, Ws, Cnt, Out);
}

// Round 5
// 73.408 us; speedup vs baseline: 1.8942x; 1.8942x over previous
//
#include <hip/hip_runtime.h>
#include <hip/hip_bf16.h>

#define DIM 8192
#define KSPLIT 16
#define PARTIAL_ELEMS (32 * DIM)   // one fp32 copy of the output per k-chunk

typedef __bf16 bf16x8 __attribute__((ext_vector_type(8)));
typedef float f32x4 __attribute__((ext_vector_type(4)));

__device__ __forceinline__ unsigned short f2bf(float f) {
  union { float f; unsigned u; } v; v.f = f;
  unsigned r = v.u + 0x7FFFu + ((v.u >> 16) & 1u);   // RNE
  return (unsigned short)(r >> 16);
}

// grid: 512 = 32 mc (low 5 bits) x 16 kc; block 256 (4 waves).
// wg: partial out cols [mc*256,+256) over k [kc*512,+512) -> Ws[kc][32][8192].
// Hot loop: 16x16x32 MFMA, BOTH operand reads are wave-contiguous 1KB ds_read_b128
// (conflict-free). Circulant trick: the two k-halves of one MFMA use adjacent
// window slots, so the blocks-fragment is the contiguous 1KB at slots [w0-1, w0+1).
// NOTE (R4 lesson): do NOT fuse the reduce via device-scope fan-in — cross-XCD
// partial reads + per-wg __threadfence cost ~80 us vs ~3 us for a second launch.
__global__ __launch_bounds__(256, 2)
void bcl_mfma_kernel(const float* __restrict__ X,
                     const float* __restrict__ Blk,
                     float* __restrict__ Ws) {
  // x: [s:16][b0:2][kh:4][p:16][j:8] bf16 (32 KB): frag = contiguous 1KB
  __shared__ __align__(16) unsigned short Xl[16384];
  // blocks window: 47 slots x 512B, each repacked [qh:2][p:16][j:8]
  __shared__ __align__(16) unsigned short Wl[47 * 256];

  const int tid = threadIdx.x;
  const int mc  = blockIdx.x & 31;
  const int kc  = blockIdx.x >> 5;
  const int kbase = kc * 512;

  // ---- stage x (fp32->bf16). LDS stores linear (conflict-free).
  #pragma unroll
  for (int it = 0; it < 16; ++it) {
    const int L  = (tid + it * 256) << 2;     // elem index in Xl
    const int j4 = L & 7;
    const int p  = (L >> 3) & 15;
    const int kh = (L >> 7) & 3;
    const int b0 = (L >> 9) & 1;
    const int s  = (L >> 10) & 15;
    const int batch = b0 * 16 + p;
    const int kg = kbase + s * 32 + (kh >> 1) * 16 + (kh & 1) * 8 + j4;
    const float4 v = *reinterpret_cast<const float4*>(X + batch * DIM + kg);
    ushort4 u;
    u.x = f2bf(v.x); u.y = f2bf(v.y); u.z = f2bf(v.z); u.w = f2bf(v.w);
    *reinterpret_cast<ushort4*>(&Xl[L]) = u;
  }

  // ---- stage blocks window: slot w holds blocks[(dbase+w)&511] as [qh][p][j]
  const int dbase = (mc * 16 - kc * 32 - 31) & 511;
  for (int i = tid; i < 47 * 64; i += 256) {
    const int w  = i >> 6;
    const int r  = (i & 63) << 2;             // elem in repacked block
    const int qh = r >> 7;
    const int p  = (r >> 3) & 15;
    const int j4 = r & 7;
    const int d  = (dbase + w) & 511;
    const float4 v = *reinterpret_cast<const float4*>(Blk + d * 256 + p * 16 + qh * 8 + j4);
    ushort4 u;
    u.x = f2bf(v.x); u.y = f2bf(v.y); u.z = f2bf(v.z); u.w = f2bf(v.w);
    *reinterpret_cast<ushort4*>(&Wl[w * 256 + r]) = u;
  }

  __syncthreads();   // only barrier

  const int lane = tid & 63;
  const int wid  = tid >> 6;

  // x-frag (a-operand): lane l -> Xl[s*1024 + b0*512 + l*8]
  const unsigned short* Xb = &Xl[lane << 3];
  // blocks-frag (b-operand): lanes 0-31 slot w0, lanes 32-63 slot w0-1, each half
  // a contiguous 512B run -> conflict-free wave-contiguous 1KB ds_read_b128
  const unsigned short* Wb = &Wl[(((lane >> 5) ^ 1) << 8) + (((lane >> 4) & 1) << 7) + ((lane & 15) << 3)];

  f32x4 acc[4][2];
  #pragma unroll
  for (int t = 0; t < 4; ++t)
    #pragma unroll
    for (int b = 0; b < 2; ++b)
      acc[t][b] = (f32x4){0.f, 0.f, 0.f, 0.f};

  #pragma unroll 4
  for (int s = 0; s < 16; ++s) {
    const bf16x8 x0 = *reinterpret_cast<const bf16x8*>(Xb + (s << 10));
    const bf16x8 x1 = *reinterpret_cast<const bf16x8*>(Xb + (s << 10) + 512);
    #pragma unroll
    for (int t = 0; t < 4; ++t) {
      const int mt = (wid << 2) + t;
      const bf16x8 wf = *reinterpret_cast<const bf16x8*>(Wb + ((mt + 30 - 2 * s) << 8));
      acc[t][0] = __builtin_amdgcn_mfma_f32_16x16x32_bf16(x0, wf, acc[t][0], 0, 0, 0);
      acc[t][1] = __builtin_amdgcn_mfma_f32_16x16x32_bf16(x1, wf, acc[t][1], 0, 0, 0);
    }
  }

  // ---- epilogue: C/D 16x16 layout col=lane&15 (=p), row=(lane>>4)*4+reg
  // each store inst: 4 rows x 16 contiguous cols (64B segments)
  float* base = Ws + (size_t)kc * PARTIAL_ELEMS + mc * 256;
  #pragma unroll
  for (int t = 0; t < 4; ++t) {
    const int col = ((wid << 2) + t) * 16 + (lane & 15);
    #pragma unroll
    for (int b0 = 0; b0 < 2; ++b0) {
      const int brow = b0 * 16 + ((lane >> 4) << 2);
      #pragma unroll
      for (int r = 0; r < 4; ++r)
        base[(brow + r) * DIM + col] = acc[t][b0][r];
    }
  }
}

// Phase 2: Out = sum of KSPLIT partials. 256 wgs x 256 thr, float4 each.
__global__ __launch_bounds__(256)
void bcl_reduce_kernel(const float4* __restrict__ Ws, float4* __restrict__ Out) {
  const int f = blockIdx.x * 256 + threadIdx.x;
  float4 a = Ws[f];
  #pragma unroll
  for (int kc = 1; kc < KSPLIT; ++kc) {
    const float4 v = Ws[kc * (PARTIAL_ELEMS / 4) + f];
    a.x += v.x; a.y += v.y; a.z += v.z; a.w += v.w;
  }
  Out[f] = a;
}

extern "C" void kernel_launch(void* const* d_in, const int* in_sizes, int n_in,
                              void* d_out, int out_size, void* d_ws, size_t ws_size,
                              hipStream_t stream) {
  const float* X   = (const float*)d_in[0];   // [32, 8192] fp32
  const float* Blk = (const float*)d_in[1];   // [512, 16, 16] fp32
  float* Ws  = (float*)d_ws;                  // 16 MB partials
  float* Out = (float*)d_out;                 // [32, 8192] fp32
  bcl_mfma_kernel<<<dim3(512), dim3(256), 0, stream>>>(X, Blk, Ws);
  bcl_reduce_kernel<<<dim3(PARTIAL_ELEMS / 4 / 256), dim3(256), 0, stream>>>(
      (const float4*)Ws, (float4*)Out);
}